// Round 11
// baseline (345.043 us; speedup 1.0000x reference)
//
#include <hip/hip_runtime.h>
#include <hip/hip_fp16.h>

// Guided filter, B=4 H=1024 W=1024 C=4 f32 NHWC, r from d_in[2] (expected <=40).
// R10->R11: occupancy fix. R10 ran 1 wave/SIMD (4 waves/CU) -> the per-row
// shfl-scan chain was fully latency-exposed (VALUBusy 19%). Now TPB=256 with
// 1 scan column/thread (208 active): same 512-block grid -> 2 blocks x 4
// waves = 8 waves/CU = 2 waves/SIMD. PPT=1 makes plane writes and window
// reads stride-1 (swizzle dropped), no exclusive shfl needed, and planes are
// double-buffered -> 2 lgkm-only barriers/row (global loads stay in flight).
// kfusedAB: I,p -> vert sliding sums {I,p,Ip,II} (regs) -> per-row block scan
//           -> horizontal box -> A,b out (fp16).
// kfusedQ : same over {A,b}; q = meanA*I + meanb -> d_out (f32).
// N = cntH(h)*cntW(w) analytic.

#define HD 1024
#define WD 1024
#define ROW4 WD
#define IMG4 ((size_t)HD * ROW4)
#define IMGF (IMG4 * 4)
#define BH 64
#define NBANDS (HD / BH)             // 16
#define TILE 128
#define NTILE (WD / TILE)            // 8
#define HALO 40
#define TPB 256
#define SCANW (TILE + 2 * HALO)      // 208
#define NPFX (SCANW + 1)             // 209 prefix entries, linear (no swizzle)
#define EPS 1e-8f

// Barrier that waits only on LDS (lgkmcnt), NOT vmcnt -> global loads stay
// in flight across it. Safe: cross-thread data flows only through LDS here.
__device__ __forceinline__ void barrier_lds() {
    asm volatile("s_waitcnt lgkmcnt(0)" ::: "memory");
    __builtin_amdgcn_s_barrier();
}

struct H4 { __half2 lo, hi; };

__device__ __forceinline__ H4 pack4(float4 v) {
    H4 h; h.lo = __floats2half2_rn(v.x, v.y); h.hi = __floats2half2_rn(v.z, v.w);
    return h;
}
__device__ __forceinline__ float4 unpack4(H4 h) {
    float2 l = __half22float2(h.lo), u = __half22float2(h.hi);
    return make_float4(l.x, l.y, u.x, u.y);
}
__device__ __forceinline__ float4 f4add(float4 a, float4 b) {
    return make_float4(a.x + b.x, a.y + b.y, a.z + b.z, a.w + b.w);
}
__device__ __forceinline__ float4 f4sub(float4 a, float4 b) {
    return make_float4(a.x - b.x, a.y - b.y, a.z - b.z, a.w - b.w);
}
__device__ __forceinline__ float4 f4s(float4 a, float s) {
    return make_float4(a.x * s, a.y * s, a.z * s, a.w * s);
}
__device__ __forceinline__ float4 f4mul(float4 a, float4 b) {
    return make_float4(a.x * b.x, a.y * b.y, a.z * b.z, a.w * b.w);
}
__device__ __forceinline__ float4 shup4(float4 v, int d) {
    return make_float4(__shfl_up(v.x, d), __shfl_up(v.y, d), __shfl_up(v.z, d), __shfl_up(v.w, d));
}
// bx in [0,128): XCD q = bx&7 gets bands {2q,2q+1} for all 8 tiles. Bijective.
__device__ __forceinline__ void decode_bx(int bx, int& tile, int& band) {
    int xcd = bx & 7, inner = bx >> 3;
    tile = inner >> 1;
    band = (xcd << 1) | (inner & 1);
}

// Block scan of 4 fields, 1 px/thread. pl/wt are this row's buffer.
// Entry(p+1) = wave-prefix + per-wave inclusive; entry 0 = 0.
__device__ __forceinline__ void scan4t(
    float4 (*pl)[NPFX], float4 (*wt)[4],
    float4 sI, float4 sp, float4 sIp, float4 sII,
    int t, int lane, int wv)
{
    const float4 z4 = make_float4(0.f, 0.f, 0.f, 0.f);
    float4 i0 = sI, i1 = sp, i2 = sIp, i3 = sII;
    #pragma unroll
    for (int d = 1; d < 64; d <<= 1) {
        float4 t0 = shup4(i0, d), t1 = shup4(i1, d), t2 = shup4(i2, d), t3 = shup4(i3, d);
        if (lane >= d) {
            i0 = f4add(i0, t0); i1 = f4add(i1, t1);
            i2 = f4add(i2, t2); i3 = f4add(i3, t3);
        }
    }
    if (lane == 63) { wt[wv][0] = i0; wt[wv][1] = i1; wt[wv][2] = i2; wt[wv][3] = i3; }
    barrier_lds();
    float4 F0 = z4, F1 = z4, F2 = z4, F3 = z4;
    if (wv > 0) { F0 = wt[0][0]; F1 = wt[0][1]; F2 = wt[0][2]; F3 = wt[0][3]; }
    if (wv > 1) {
        F0 = f4add(F0, wt[1][0]); F1 = f4add(F1, wt[1][1]);
        F2 = f4add(F2, wt[1][2]); F3 = f4add(F3, wt[1][3]);
    }
    if (wv > 2) {
        F0 = f4add(F0, wt[2][0]); F1 = f4add(F1, wt[2][1]);
        F2 = f4add(F2, wt[2][2]); F3 = f4add(F3, wt[2][3]);
    }
    if (t == 0) { pl[0][0] = z4; pl[1][0] = z4; pl[2][0] = z4; pl[3][0] = z4; }
    if (t < SCANW) {
        pl[0][t + 1] = f4add(F0, i0);
        pl[1][t + 1] = f4add(F1, i1);
        pl[2][t + 1] = f4add(F2, i2);
        pl[3][t + 1] = f4add(F3, i3);
    }
    barrier_lds();
}

__device__ __forceinline__ void scan2t(
    float4 (*pl)[NPFX], float4 (*wt)[2],
    float4 sA, float4 sB, int t, int lane, int wv)
{
    const float4 z4 = make_float4(0.f, 0.f, 0.f, 0.f);
    float4 i0 = sA, i1 = sB;
    #pragma unroll
    for (int d = 1; d < 64; d <<= 1) {
        float4 t0 = shup4(i0, d), t1 = shup4(i1, d);
        if (lane >= d) { i0 = f4add(i0, t0); i1 = f4add(i1, t1); }
    }
    if (lane == 63) { wt[wv][0] = i0; wt[wv][1] = i1; }
    barrier_lds();
    float4 F0 = z4, F1 = z4;
    if (wv > 0) { F0 = wt[0][0]; F1 = wt[0][1]; }
    if (wv > 1) { F0 = f4add(F0, wt[1][0]); F1 = f4add(F1, wt[1][1]); }
    if (wv > 2) { F0 = f4add(F0, wt[2][0]); F1 = f4add(F1, wt[2][1]); }
    if (t == 0) { pl[0][0] = z4; pl[1][0] = z4; }
    if (t < SCANW) {
        pl[0][t + 1] = f4add(F0, i0);
        pl[1][t + 1] = f4add(F1, i1);
    }
    barrier_lds();
}

// ---------------- KA: I,p -> A,b (fp16) ----------------
__global__ __launch_bounds__(TPB, 2) void kfusedAB(
    const float4* __restrict__ I4, const float4* __restrict__ P4,
    H4* __restrict__ Aout, H4* __restrict__ Bout,
    const int* __restrict__ rptr)
{
    __shared__ float4 pl[2][4][NPFX];   // double-buffered planes, 26.8 KB
    __shared__ float4 wt[2][4][4];
    const int r = *rptr;
    const int t = threadIdx.x, lane = t & 63, wv = t >> 6;
    int tile, band; decode_bx(blockIdx.x, tile, band);
    const int h0 = band * BH;
    const int T = tile * TILE;
    const int seg0 = T - HALO;
    const size_t imgb = (size_t)blockIdx.y * IMG4;
    const float4* Iimg = I4 + imgb;
    const float4* Pimg = P4 + imgb;
    const float4 z4 = make_float4(0.f, 0.f, 0.f, 0.f);

    // this thread's scan column
    const int c = seg0 + t;
    const bool ok = (t < SCANW) && (c >= 0) && (c < WD);
    const float cw = ok ? 1.f : 0.f;
    const int cc = ok ? c : 0;

    // this thread's output pixel (if any) + fixed window indices
    const bool outAct = (t >= HALO) && (t < HALO + TILE);
    const int w = seg0 + t;
    int wl = w - r; if (wl < 0) wl = 0;
    int wh = w + r; if (wh > WD - 1) wh = WD - 1;
    const float cntW = (float)(wh - wl + 1);
    const int iA = wh + 1 - seg0, iB = wl - seg0;   // valid when outAct

    float4 sI = z4, sp = z4, sIp = z4, sII = z4;
    int lo = h0 - r; if (lo < 0) lo = 0;
    int hi = h0 + r; if (hi > HD - 1) hi = HD - 1;
    int j = lo;
    for (; j + 3 <= hi; j += 4) {
        float4 a[4], p[4];
        #pragma unroll
        for (int k = 0; k < 4; ++k) {
            a[k] = f4s(Iimg[(size_t)(j + k) * ROW4 + cc], cw);
            p[k] = f4s(Pimg[(size_t)(j + k) * ROW4 + cc], cw);
        }
        #pragma unroll
        for (int k = 0; k < 4; ++k) {
            sI = f4add(sI, a[k]); sp = f4add(sp, p[k]);
            sIp = f4add(sIp, f4mul(a[k], p[k]));
            sII = f4add(sII, f4mul(a[k], a[k]));
        }
    }
    for (; j <= hi; ++j) {
        float4 a = f4s(Iimg[(size_t)j * ROW4 + cc], cw);
        float4 p = f4s(Pimg[(size_t)j * ROW4 + cc], cw);
        sI = f4add(sI, a); sp = f4add(sp, p);
        sIp = f4add(sIp, f4mul(a, p));
        sII = f4add(sII, f4mul(a, a));
    }

    for (int h = h0; h < h0 + BH; ++h) {
        const int buf = h & 1;
        // early-issue slide loads (complete during the scan; barriers are
        // lgkm-only so they stay in flight)
        int ja = h + 1 + r, js = h - r;
        float wa  = (ja <= HD - 1) ? 1.f : 0.f;
        float wsb = (js >= 0) ? 1.f : 0.f;
        int jac = (ja <= HD - 1) ? ja : HD - 1;
        int jsc = (js >= 0) ? js : 0;
        float4 La = Iimg[(size_t)jac * ROW4 + cc];
        float4 Ca = Pimg[(size_t)jac * ROW4 + cc];
        float4 Ls = Iimg[(size_t)jsc * ROW4 + cc];
        float4 Cs = Pimg[(size_t)jsc * ROW4 + cc];

        int hl = h - r; if (hl < 0) hl = 0;
        int hh = h + r; if (hh > HD - 1) hh = HD - 1;
        const float cntH = (float)(hh - hl + 1);

        scan4t(pl[buf], wt[buf], sI, sp, sIp, sII, t, lane, wv);

        if (outAct) {
            float invN = 1.f / (cntW * cntH);
            float4 mI  = f4s(f4sub(pl[buf][0][iA], pl[buf][0][iB]), invN);
            float4 mp  = f4s(f4sub(pl[buf][1][iA], pl[buf][1][iB]), invN);
            float4 mIp = f4s(f4sub(pl[buf][2][iA], pl[buf][2][iB]), invN);
            float4 mII = f4s(f4sub(pl[buf][3][iA], pl[buf][3][iB]), invN);
            float4 cov = f4sub(mIp, f4mul(mI, mp));
            float4 var = f4sub(mII, f4mul(mI, mI));
            float4 Av = make_float4(cov.x / (var.x + EPS), cov.y / (var.y + EPS),
                                    cov.z / (var.z + EPS), cov.w / (var.w + EPS));
            float4 Bv = f4sub(mp, f4mul(Av, mI));
            Aout[imgb + (size_t)h * ROW4 + w] = pack4(Av);
            Bout[imgb + (size_t)h * ROW4 + w] = pack4(Bv);
        }
        // no barrier here: next row uses the other plane buffer

        float4 A1 = f4s(La, wa * cw),  C1 = f4s(Ca, wa * cw);
        float4 A2 = f4s(Ls, wsb * cw), C2 = f4s(Cs, wsb * cw);
        sI = f4add(f4sub(sI, A2), A1);
        sp = f4add(f4sub(sp, C2), C1);
        sIp = f4add(sIp, f4sub(f4mul(A1, C1), f4mul(A2, C2)));
        sII = f4add(sII, f4sub(f4mul(A1, A1), f4mul(A2, A2)));
    }
}

// ---------------- KB: A,b -> q = meanA*I + meanb ----------------
__global__ __launch_bounds__(TPB, 2) void kfusedQ(
    const H4* __restrict__ Ain, const H4* __restrict__ Bin,
    const float4* __restrict__ I4, float4* __restrict__ Qout,
    const int* __restrict__ rptr)
{
    __shared__ float4 pl[2][2][NPFX];   // 13.4 KB
    __shared__ float4 wt[2][4][2];
    const int r = *rptr;
    const int t = threadIdx.x, lane = t & 63, wv = t >> 6;
    int tile, band; decode_bx(blockIdx.x, tile, band);
    const int h0 = band * BH;
    const int T = tile * TILE;
    const int seg0 = T - HALO;
    const size_t imgb = (size_t)blockIdx.y * IMG4;
    const H4* Aimg = Ain + imgb;
    const H4* Bimg = Bin + imgb;
    const float4* Iimg = I4 + imgb;
    const float4 z4 = make_float4(0.f, 0.f, 0.f, 0.f);

    const int c = seg0 + t;
    const bool ok = (t < SCANW) && (c >= 0) && (c < WD);
    const float cw = ok ? 1.f : 0.f;
    const int cc = ok ? c : 0;

    const bool outAct = (t >= HALO) && (t < HALO + TILE);
    const int w = seg0 + t;
    int wl = w - r; if (wl < 0) wl = 0;
    int wh = w + r; if (wh > WD - 1) wh = WD - 1;
    const float cntW = (float)(wh - wl + 1);
    const int iA = wh + 1 - seg0, iB = wl - seg0;

    float4 sA = z4, sB = z4;
    int lo = h0 - r; if (lo < 0) lo = 0;
    int hi = h0 + r; if (hi > HD - 1) hi = HD - 1;
    int j = lo;
    for (; j + 3 <= hi; j += 4) {
        H4 a[4], b[4];
        #pragma unroll
        for (int k = 0; k < 4; ++k) {
            a[k] = Aimg[(size_t)(j + k) * ROW4 + cc];
            b[k] = Bimg[(size_t)(j + k) * ROW4 + cc];
        }
        #pragma unroll
        for (int k = 0; k < 4; ++k) {
            sA = f4add(sA, f4s(unpack4(a[k]), cw));
            sB = f4add(sB, f4s(unpack4(b[k]), cw));
        }
    }
    for (; j <= hi; ++j) {
        sA = f4add(sA, f4s(unpack4(Aimg[(size_t)j * ROW4 + cc]), cw));
        sB = f4add(sB, f4s(unpack4(Bimg[(size_t)j * ROW4 + cc]), cw));
    }

    for (int h = h0; h < h0 + BH; ++h) {
        const int buf = h & 1;
        int ja = h + 1 + r, js = h - r;
        float wa  = (ja <= HD - 1) ? 1.f : 0.f;
        float wsb = (js >= 0) ? 1.f : 0.f;
        int jac = (ja <= HD - 1) ? ja : HD - 1;
        int jsc = (js >= 0) ? js : 0;
        H4 La = Aimg[(size_t)jac * ROW4 + cc];
        H4 Lb = Bimg[(size_t)jac * ROW4 + cc];
        H4 Sa = Aimg[(size_t)jsc * ROW4 + cc];
        H4 Sb = Bimg[(size_t)jsc * ROW4 + cc];
        float4 iv = outAct ? Iimg[(size_t)h * ROW4 + w] : z4;

        int hl = h - r; if (hl < 0) hl = 0;
        int hh = h + r; if (hh > HD - 1) hh = HD - 1;
        const float cntH = (float)(hh - hl + 1);

        scan2t(pl[buf], wt[buf], sA, sB, t, lane, wv);

        if (outAct) {
            float invN = 1.f / (cntW * cntH);
            float4 mA = f4s(f4sub(pl[buf][0][iA], pl[buf][0][iB]), invN);
            float4 mB = f4s(f4sub(pl[buf][1][iA], pl[buf][1][iB]), invN);
            Qout[imgb + (size_t)h * ROW4 + w] =
                make_float4(mA.x * iv.x + mB.x, mA.y * iv.y + mB.y,
                            mA.z * iv.z + mB.z, mA.w * iv.w + mB.w);
        }

        float4 A1 = f4s(unpack4(La), wa * cw);
        float4 B1 = f4s(unpack4(Lb), wa * cw);
        float4 A2 = f4s(unpack4(Sa), wsb * cw);
        float4 B2 = f4s(unpack4(Sb), wsb * cw);
        sA = f4add(f4sub(sA, A2), A1);
        sB = f4add(f4sub(sB, B2), B1);
    }
}

extern "C" void kernel_launch(void* const* d_in, const int* in_sizes, int n_in,
                              void* d_out, int out_size, void* d_ws, size_t ws_size,
                              hipStream_t stream)
{
    const float* I = (const float*)d_in[0];
    const float* P = (const float*)d_in[1];
    const int* rptr = (const int*)d_in[2];
    float* out = (float*)d_out;

    const int Bn = (int)(in_sizes[0] / IMGF);
    const size_t perBatch = 2 * IMG4 * sizeof(H4);

    int nbChunk = (int)(ws_size / perBatch);
    if (nbChunk < 1) nbChunk = 1;
    if (nbChunk > Bn) nbChunk = Bn;

    for (int b0 = 0; b0 < Bn; b0 += nbChunk) {
        const int nb = (b0 + nbChunk <= Bn) ? nbChunk : (Bn - b0);
        H4* Ah = (H4*)d_ws;
        H4* Bh = Ah + (size_t)nb * IMG4;
        const float4* Ib = (const float4*)(I + (size_t)b0 * IMGF);
        const float4* Pb = (const float4*)(P + (size_t)b0 * IMGF);
        float4* ob = (float4*)(out + (size_t)b0 * IMGF);

        dim3 grid(NTILE * NBANDS, nb);
        kfusedAB<<<grid, TPB, 0, stream>>>(Ib, Pb, Ah, Bh, rptr);
        kfusedQ<<<grid, TPB, 0, stream>>>(Ah, Bh, Ib, ob, rptr);
    }
}

// Round 12
// 248.996 us; speedup vs baseline: 1.3857x; 1.3857x over previous
//
#include <hip/hip_runtime.h>
#include <hip/hip_fp16.h>

// Guided filter, B=4 H=1024 W=1024 C=4 f32 NHWC, r from d_in[2] (expected <=40).
// R12 = R5 geometry (best measured: full-width 256-thread blocks, PPT=4,
// BH=16, 256 blocks = 1/CU, idx4-swizzled LDS planes) + lessons from R9-R11:
//  - lgkm-only barriers (R5's __syncthreads drained the slide prefetch with
//    vmcnt(0) at every barrier; loads now ride through and overlap the scan)
//  - double-buffered planes -> 2 barriers/row (was 3)
//  - warm-up batched 4 rows (32 loads in flight)
//  - XCD band-grouping swizzle (adjacent bands share 80 warm-up rows)
//  - A,b stores vectorized to 2x float4 (32B/lane contiguous)
// kfusedAB: I,p -> vert sliding sums {I,p,Ip,II} (regs) -> per-row block scan
//           -> horizontal box -> A,b out (fp16).
// kfusedQ : same over {A,b}; q = meanA*I + meanb -> d_out (f32).
// N = cntH(h)*cntW(w) analytic.

#define HD 1024
#define WD 1024
#define ROW4 WD                      // float4 pixels per row
#define IMG4 ((size_t)HD * ROW4)
#define IMGF (IMG4 * 4)
#define BH 16                        // output rows per block
#define NB (HD / BH)                 // 64 bands
#define TPB 256
#define PPT 4                        // pixels per thread (full width)
#define PFXN 1153                    // idx4(1024)+1
#define EPS 1e-8f

__device__ __forceinline__ int idx4(int p) { return p + (p >> 3); }

// lgkm-only barrier: waits LDS ops, NOT global loads (vmcnt) -> prefetched
// slide loads stay in flight across it. Cross-thread data flows only via LDS.
__device__ __forceinline__ void barrier_lds() {
    asm volatile("s_waitcnt lgkmcnt(0)" ::: "memory");
    __builtin_amdgcn_s_barrier();
}

struct H4 { __half2 lo, hi; };

__device__ __forceinline__ H4 pack4(float4 v) {
    H4 h; h.lo = __floats2half2_rn(v.x, v.y); h.hi = __floats2half2_rn(v.z, v.w);
    return h;
}
__device__ __forceinline__ float4 unpack4(H4 h) {
    float2 l = __half22float2(h.lo), u = __half22float2(h.hi);
    return make_float4(l.x, l.y, u.x, u.y);
}
__device__ __forceinline__ float4 packAB(H4 a, H4 b) {
    union { H4 h[2]; float4 f; } u; u.h[0] = a; u.h[1] = b; return u.f;
}
__device__ __forceinline__ float4 f4add(float4 a, float4 b) {
    return make_float4(a.x + b.x, a.y + b.y, a.z + b.z, a.w + b.w);
}
__device__ __forceinline__ float4 f4sub(float4 a, float4 b) {
    return make_float4(a.x - b.x, a.y - b.y, a.z - b.z, a.w - b.w);
}
__device__ __forceinline__ float4 f4s(float4 a, float s) {
    return make_float4(a.x * s, a.y * s, a.z * s, a.w * s);
}
__device__ __forceinline__ float4 f4mul(float4 a, float4 b) {
    return make_float4(a.x * b.x, a.y * b.y, a.z * b.z, a.w * b.w);
}
__device__ __forceinline__ float4 shup4(float4 v, int d) {
    return make_float4(__shfl_up(v.x, d), __shfl_up(v.y, d), __shfl_up(v.z, d), __shfl_up(v.w, d));
}
// 64 bands: XCD q = bx&7 gets bands 8q..8q+7 (adjacent bands share warm-up
// rows -> per-XCD L2 locality). Bijective.
__device__ __forceinline__ int band_of(int bx) {
    return (bx >> 3) + (bx & 7) * 8;
}

// Block scan of 4 fields (PPT=4/thread) into swizzled planes pl[f][idx4(p)],
// entry 0 = 0. 2 lgkm barriers; no barrier after (planes double-buffered).
__device__ __forceinline__ void scan4d(
    float4 (*pl)[PFXN], float4 (*wt)[4],
    const float4* s0, const float4* s1, const float4* s2, const float4* s3,
    int t, int lane, int wv)
{
    const float4 z4 = make_float4(0.f, 0.f, 0.f, 0.f);
    float4 p0[PPT], p1[PPT], p2[PPT], p3[PPT];
    p0[0] = s0[0]; p1[0] = s1[0]; p2[0] = s2[0]; p3[0] = s3[0];
    #pragma unroll
    for (int i = 1; i < PPT; ++i) {
        p0[i] = f4add(p0[i-1], s0[i]); p1[i] = f4add(p1[i-1], s1[i]);
        p2[i] = f4add(p2[i-1], s2[i]); p3[i] = f4add(p3[i-1], s3[i]);
    }
    float4 i0 = p0[3], i1 = p1[3], i2 = p2[3], i3 = p3[3];
    #pragma unroll
    for (int d = 1; d < 64; d <<= 1) {
        float4 t0 = shup4(i0, d), t1 = shup4(i1, d), t2 = shup4(i2, d), t3 = shup4(i3, d);
        if (lane >= d) {
            i0 = f4add(i0, t0); i1 = f4add(i1, t1);
            i2 = f4add(i2, t2); i3 = f4add(i3, t3);
        }
    }
    float4 e0 = shup4(i0, 1), e1 = shup4(i1, 1), e2 = shup4(i2, 1), e3 = shup4(i3, 1);
    if (lane == 0) { e0 = z4; e1 = z4; e2 = z4; e3 = z4; }
    if (lane == 63) { wt[wv][0] = i0; wt[wv][1] = i1; wt[wv][2] = i2; wt[wv][3] = i3; }
    barrier_lds();
    for (int wq = 0; wq < wv; ++wq) {
        e0 = f4add(e0, wt[wq][0]); e1 = f4add(e1, wt[wq][1]);
        e2 = f4add(e2, wt[wq][2]); e3 = f4add(e3, wt[wq][3]);
    }
    if (t == 0) {
        pl[0][idx4(0)] = z4; pl[1][idx4(0)] = z4;
        pl[2][idx4(0)] = z4; pl[3][idx4(0)] = z4;
    }
    #pragma unroll
    for (int i = 0; i < PPT; ++i) {
        int p = PPT * t + 1 + i;
        pl[0][idx4(p)] = f4add(e0, p0[i]);
        pl[1][idx4(p)] = f4add(e1, p1[i]);
        pl[2][idx4(p)] = f4add(e2, p2[i]);
        pl[3][idx4(p)] = f4add(e3, p3[i]);
    }
    barrier_lds();
}

__device__ __forceinline__ void scan2d(
    float4 (*pl)[PFXN], float4 (*wt)[2],
    const float4* s0, const float4* s1, int t, int lane, int wv)
{
    const float4 z4 = make_float4(0.f, 0.f, 0.f, 0.f);
    float4 p0[PPT], p1[PPT];
    p0[0] = s0[0]; p1[0] = s1[0];
    #pragma unroll
    for (int i = 1; i < PPT; ++i) {
        p0[i] = f4add(p0[i-1], s0[i]); p1[i] = f4add(p1[i-1], s1[i]);
    }
    float4 i0 = p0[3], i1 = p1[3];
    #pragma unroll
    for (int d = 1; d < 64; d <<= 1) {
        float4 t0 = shup4(i0, d), t1 = shup4(i1, d);
        if (lane >= d) { i0 = f4add(i0, t0); i1 = f4add(i1, t1); }
    }
    float4 e0 = shup4(i0, 1), e1 = shup4(i1, 1);
    if (lane == 0) { e0 = z4; e1 = z4; }
    if (lane == 63) { wt[wv][0] = i0; wt[wv][1] = i1; }
    barrier_lds();
    for (int wq = 0; wq < wv; ++wq) {
        e0 = f4add(e0, wt[wq][0]); e1 = f4add(e1, wt[wq][1]);
    }
    if (t == 0) { pl[0][idx4(0)] = z4; pl[1][idx4(0)] = z4; }
    #pragma unroll
    for (int i = 0; i < PPT; ++i) {
        int p = PPT * t + 1 + i;
        pl[0][idx4(p)] = f4add(e0, p0[i]);
        pl[1][idx4(p)] = f4add(e1, p1[i]);
    }
    barrier_lds();
}

// ---------------- KA: I,p -> A,b (fp16) ----------------
__global__ __launch_bounds__(TPB, 1) void kfusedAB(
    const float4* __restrict__ I4, const float4* __restrict__ P4,
    H4* __restrict__ Aout, H4* __restrict__ Bout,
    const int* __restrict__ rptr)
{
    __shared__ float4 pl[2][4][PFXN];   // double-buffered planes, 147.6 KB
    __shared__ float4 wt[2][4][4];
    const int r = *rptr;
    const int t = threadIdx.x, lane = t & 63, wv = t >> 6;
    const int h0 = band_of(blockIdx.x) * BH;
    const size_t imgb = (size_t)blockIdx.y * IMG4;
    const float4* Ib = I4 + imgb + PPT * t;
    const float4* Pb = P4 + imgb + PPT * t;
    H4* Ao = Aout + imgb;
    H4* Bo = Bout + imgb;
    const float4 z4 = make_float4(0.f, 0.f, 0.f, 0.f);

    float4 sI[PPT], sp[PPT], sIp[PPT], sII[PPT];
    #pragma unroll
    for (int i = 0; i < PPT; ++i) { sI[i] = z4; sp[i] = z4; sIp[i] = z4; sII[i] = z4; }

    int lo = h0 - r; if (lo < 0) lo = 0;
    int hi = h0 + r; if (hi > HD - 1) hi = HD - 1;
    // warm-up, 4-row batches (32 loads in flight)
    int j = lo;
    for (; j + 3 <= hi; j += 4) {
        float4 a[4][PPT], c[4][PPT];
        #pragma unroll
        for (int k = 0; k < 4; ++k) {
            const float4* Ir = Ib + (size_t)(j + k) * ROW4;
            const float4* Pr = Pb + (size_t)(j + k) * ROW4;
            #pragma unroll
            for (int i = 0; i < PPT; ++i) { a[k][i] = Ir[i]; c[k][i] = Pr[i]; }
        }
        #pragma unroll
        for (int k = 0; k < 4; ++k)
            #pragma unroll
            for (int i = 0; i < PPT; ++i) {
                sI[i] = f4add(sI[i], a[k][i]);
                sp[i] = f4add(sp[i], c[k][i]);
                sIp[i] = f4add(sIp[i], f4mul(a[k][i], c[k][i]));
                sII[i] = f4add(sII[i], f4mul(a[k][i], a[k][i]));
            }
    }
    for (; j <= hi; ++j) {
        const float4* Ir = Ib + (size_t)j * ROW4;
        const float4* Pr = Pb + (size_t)j * ROW4;
        #pragma unroll
        for (int i = 0; i < PPT; ++i) {
            float4 a = Ir[i], c = Pr[i];
            sI[i] = f4add(sI[i], a); sp[i] = f4add(sp[i], c);
            sIp[i] = f4add(sIp[i], f4mul(a, c));
            sII[i] = f4add(sII[i], f4mul(a, a));
        }
    }

    for (int h = h0; h < h0 + BH; ++h) {
        const int buf = h & 1;
        // early-issue slide loads; lgkm barriers let them ride through the scan
        int ja = h + 1 + r, js = h - r;
        float wa  = (ja <= HD - 1) ? 1.f : 0.f;
        float wsb = (js >= 0) ? 1.f : 0.f;
        int jac = (ja <= HD - 1) ? ja : HD - 1;
        int jsc = (js >= 0) ? js : 0;
        const float4* Iar = Ib + (size_t)jac * ROW4;
        const float4* Par = Pb + (size_t)jac * ROW4;
        const float4* Isr = Ib + (size_t)jsc * ROW4;
        const float4* Psr = Pb + (size_t)jsc * ROW4;
        float4 La[PPT], Ca[PPT], Ls[PPT], Cs[PPT];
        #pragma unroll
        for (int i = 0; i < PPT; ++i) {
            La[i] = Iar[i]; Ca[i] = Par[i];
            Ls[i] = Isr[i]; Cs[i] = Psr[i];
        }

        int hl = h - r; if (hl < 0) hl = 0;
        int hh = h + r; if (hh > HD - 1) hh = HD - 1;
        const float cntH = (float)(hh - hl + 1);

        scan4d(pl[buf], wt[buf], sI, sp, sIp, sII, t, lane, wv);

        H4 av[PPT], bv[PPT];
        #pragma unroll
        for (int i = 0; i < PPT; ++i) {
            int wp = PPT * t + i;
            int wl = wp - r; if (wl < 0) wl = 0;
            int wh2 = wp + r; if (wh2 > WD - 1) wh2 = WD - 1;
            float invN = 1.f / ((float)(wh2 - wl + 1) * cntH);
            int iA = idx4(wh2 + 1), iB = idx4(wl);
            float4 mI  = f4s(f4sub(pl[buf][0][iA], pl[buf][0][iB]), invN);
            float4 mp  = f4s(f4sub(pl[buf][1][iA], pl[buf][1][iB]), invN);
            float4 mIp = f4s(f4sub(pl[buf][2][iA], pl[buf][2][iB]), invN);
            float4 mII = f4s(f4sub(pl[buf][3][iA], pl[buf][3][iB]), invN);
            float4 cov = f4sub(mIp, f4mul(mI, mp));
            float4 var = f4sub(mII, f4mul(mI, mI));
            float4 Av = make_float4(cov.x / (var.x + EPS), cov.y / (var.y + EPS),
                                    cov.z / (var.z + EPS), cov.w / (var.w + EPS));
            float4 Bv = f4sub(mp, f4mul(Av, mI));
            av[i] = pack4(Av); bv[i] = pack4(Bv);
        }
        // 32B/lane contiguous stores (2x dwordx4 each)
        {
            float4* Arow = (float4*)(Ao + (size_t)h * ROW4 + PPT * t);
            float4* Brow = (float4*)(Bo + (size_t)h * ROW4 + PPT * t);
            Arow[0] = packAB(av[0], av[1]); Arow[1] = packAB(av[2], av[3]);
            Brow[0] = packAB(bv[0], bv[1]); Brow[1] = packAB(bv[2], bv[3]);
        }
        // no barrier: next row uses the other plane buffer

        #pragma unroll
        for (int i = 0; i < PPT; ++i) {
            float4 A1 = f4s(La[i], wa),  C1 = f4s(Ca[i], wa);
            float4 A2 = f4s(Ls[i], wsb), C2 = f4s(Cs[i], wsb);
            sI[i] = f4add(f4sub(sI[i], A2), A1);
            sp[i] = f4add(f4sub(sp[i], C2), C1);
            sIp[i] = f4add(sIp[i], f4sub(f4mul(A1, C1), f4mul(A2, C2)));
            sII[i] = f4add(sII[i], f4sub(f4mul(A1, A1), f4mul(A2, A2)));
        }
    }
}

// ---------------- KB: A,b -> q = meanA*I + meanb ----------------
__global__ __launch_bounds__(TPB, 1) void kfusedQ(
    const H4* __restrict__ Ain, const H4* __restrict__ Bin,
    const float4* __restrict__ I4, float4* __restrict__ Qout,
    const int* __restrict__ rptr)
{
    __shared__ float4 pl[2][2][PFXN];   // 73.8 KB
    __shared__ float4 wt[2][4][2];
    const int r = *rptr;
    const int t = threadIdx.x, lane = t & 63, wv = t >> 6;
    const int h0 = band_of(blockIdx.x) * BH;
    const size_t imgb = (size_t)blockIdx.y * IMG4;
    const H4* Abp = Ain + imgb + PPT * t;
    const H4* Bbp = Bin + imgb + PPT * t;
    const float4* Ib = I4 + imgb + PPT * t;
    float4* Qo = Qout + imgb;
    const float4 z4 = make_float4(0.f, 0.f, 0.f, 0.f);

    float4 sA[PPT], sB[PPT];
    #pragma unroll
    for (int i = 0; i < PPT; ++i) { sA[i] = z4; sB[i] = z4; }

    int lo = h0 - r; if (lo < 0) lo = 0;
    int hi = h0 + r; if (hi > HD - 1) hi = HD - 1;
    int j = lo;
    for (; j + 3 <= hi; j += 4) {
        H4 a[4][PPT], b[4][PPT];
        #pragma unroll
        for (int k = 0; k < 4; ++k) {
            const H4* Ar = Abp + (size_t)(j + k) * ROW4;
            const H4* Br = Bbp + (size_t)(j + k) * ROW4;
            #pragma unroll
            for (int i = 0; i < PPT; ++i) { a[k][i] = Ar[i]; b[k][i] = Br[i]; }
        }
        #pragma unroll
        for (int k = 0; k < 4; ++k)
            #pragma unroll
            for (int i = 0; i < PPT; ++i) {
                sA[i] = f4add(sA[i], unpack4(a[k][i]));
                sB[i] = f4add(sB[i], unpack4(b[k][i]));
            }
    }
    for (; j <= hi; ++j) {
        const H4* Ar = Abp + (size_t)j * ROW4;
        const H4* Br = Bbp + (size_t)j * ROW4;
        #pragma unroll
        for (int i = 0; i < PPT; ++i) {
            sA[i] = f4add(sA[i], unpack4(Ar[i]));
            sB[i] = f4add(sB[i], unpack4(Br[i]));
        }
    }

    for (int h = h0; h < h0 + BH; ++h) {
        const int buf = h & 1;
        int ja = h + 1 + r, js = h - r;
        float wa  = (ja <= HD - 1) ? 1.f : 0.f;
        float wsb = (js >= 0) ? 1.f : 0.f;
        int jac = (ja <= HD - 1) ? ja : HD - 1;
        int jsc = (js >= 0) ? js : 0;
        const H4* Aar = Abp + (size_t)jac * ROW4;
        const H4* Bar = Bbp + (size_t)jac * ROW4;
        const H4* Asr = Abp + (size_t)jsc * ROW4;
        const H4* Bsr = Bbp + (size_t)jsc * ROW4;
        const float4* Irow = Ib + (size_t)h * ROW4;
        H4 La[PPT], Lb[PPT], Sa[PPT], Sb[PPT];
        float4 iv[PPT];
        #pragma unroll
        for (int i = 0; i < PPT; ++i) {
            La[i] = Aar[i]; Lb[i] = Bar[i];
            Sa[i] = Asr[i]; Sb[i] = Bsr[i];
            iv[i] = Irow[i];
        }

        int hl = h - r; if (hl < 0) hl = 0;
        int hh = h + r; if (hh > HD - 1) hh = HD - 1;
        const float cntH = (float)(hh - hl + 1);

        scan2d(pl[buf], wt[buf], sA, sB, t, lane, wv);

        float4* Qrow = Qo + (size_t)h * ROW4 + PPT * t;
        #pragma unroll
        for (int i = 0; i < PPT; ++i) {
            int wp = PPT * t + i;
            int wl = wp - r; if (wl < 0) wl = 0;
            int wh2 = wp + r; if (wh2 > WD - 1) wh2 = WD - 1;
            float invN = 1.f / ((float)(wh2 - wl + 1) * cntH);
            int iA = idx4(wh2 + 1), iB = idx4(wl);
            float4 mA = f4s(f4sub(pl[buf][0][iA], pl[buf][0][iB]), invN);
            float4 mB = f4s(f4sub(pl[buf][1][iA], pl[buf][1][iB]), invN);
            Qrow[i] = make_float4(mA.x * iv[i].x + mB.x, mA.y * iv[i].y + mB.y,
                                  mA.z * iv[i].z + mB.z, mA.w * iv[i].w + mB.w);
        }

        #pragma unroll
        for (int i = 0; i < PPT; ++i) {
            float4 A1 = f4s(unpack4(La[i]), wa);
            float4 B1 = f4s(unpack4(Lb[i]), wa);
            float4 A2 = f4s(unpack4(Sa[i]), wsb);
            float4 B2 = f4s(unpack4(Sb[i]), wsb);
            sA[i] = f4add(f4sub(sA[i], A2), A1);
            sB[i] = f4add(f4sub(sB[i], B2), B1);
        }
    }
}

extern "C" void kernel_launch(void* const* d_in, const int* in_sizes, int n_in,
                              void* d_out, int out_size, void* d_ws, size_t ws_size,
                              hipStream_t stream)
{
    const float* I = (const float*)d_in[0];
    const float* P = (const float*)d_in[1];
    const int* rptr = (const int*)d_in[2];
    float* out = (float*)d_out;

    const int Bn = (int)(in_sizes[0] / IMGF);              // 4
    const size_t perBatch = 2 * IMG4 * sizeof(H4);         // A,b fp16 = 16 MiB

    int nbChunk = (int)(ws_size / perBatch);
    if (nbChunk < 1) nbChunk = 1;
    if (nbChunk > Bn) nbChunk = Bn;

    for (int b0 = 0; b0 < Bn; b0 += nbChunk) {
        const int nb = (b0 + nbChunk <= Bn) ? nbChunk : (Bn - b0);
        H4* Ah = (H4*)d_ws;
        H4* Bh = Ah + (size_t)nb * IMG4;
        const float4* Ib = (const float4*)(I + (size_t)b0 * IMGF);
        const float4* Pb = (const float4*)(P + (size_t)b0 * IMGF);
        float4* ob = (float4*)(out + (size_t)b0 * IMGF);

        dim3 grid(NB, nb);                                 // 64 x nb
        kfusedAB<<<grid, TPB, 0, stream>>>(Ib, Pb, Ah, Bh, rptr);
        kfusedQ<<<grid, TPB, 0, stream>>>(Ah, Bh, Ib, ob, rptr);
    }
}